// Round 13
// baseline (761.978 us; speedup 1.0000x reference)
//
#include <hip/hip_runtime.h>

#define NN 100000
#define EE 1600000
#define BB 256
#define IN_F 7
#define HH 128
#define NBKT 391        // ceil(NN/256) buckets for binned CSR fill
#define BIN_CHUNK 4096  // edges per bin_edges2 block

typedef unsigned int uint;
typedef unsigned short ushort;
typedef __attribute__((ext_vector_type(8))) short short8;
typedef __attribute__((ext_vector_type(4))) float f32x4;

// ---------------- bf16 helpers ----------------

__device__ __forceinline__ float bflo(uint u) { return __uint_as_float(u << 16); }
__device__ __forceinline__ float bfhi(uint u) { return __uint_as_float(u & 0xFFFF0000u); }
__device__ __forceinline__ ushort f2bf(float x) {   // RNE; inputs finite
    uint u = __float_as_uint(x);
    u = (u + 0x7FFFu + ((u >> 16) & 1u)) >> 16;
    return (ushort)u;
}

// ---------------- CSR build ----------------

__global__ void count_deg(const int* __restrict__ ei, int* __restrict__ deg, int e) {
    int i = blockIdx.x * 256 + threadIdx.x;
    if (i < e) atomicAdd(&deg[ei[e + i]], 1);   // dst = ei[E + i]
}

__global__ void scan_partial(const int* __restrict__ deg, int* __restrict__ bsum, int n) {
    __shared__ int sd[256];
    int b = blockIdx.x, t = threadIdx.x;
    int base = b * 1024 + t * 4;
    int s = 0;
    #pragma unroll
    for (int k = 0; k < 4; ++k) { int i = base + k; if (i < n) s += deg[i]; }
    sd[t] = s; __syncthreads();
    for (int off = 128; off > 0; off >>= 1) {
        if (t < off) sd[t] += sd[t + off];
        __syncthreads();
    }
    if (t == 0) bsum[b] = sd[0];
}

__global__ void scan_bsum(int* __restrict__ bsum, int nb) {
    __shared__ int sd[256];
    int t = threadIdx.x;
    int v = (t < nb) ? bsum[t] : 0;
    sd[t] = v; __syncthreads();
    for (int off = 1; off < 256; off <<= 1) {
        int add = (t >= off) ? sd[t - off] : 0;
        __syncthreads();
        sd[t] += add;
        __syncthreads();
    }
    if (t < nb) bsum[t] = sd[t] - v;   // exclusive
}

__global__ void scan_apply(const int* __restrict__ deg, const int* __restrict__ bsum,
                           int* __restrict__ rowptr, int n, int e) {
    __shared__ int sd[256];
    int b = blockIdx.x, t = threadIdx.x;
    int base = b * 1024 + t * 4;
    int v[4]; int s = 0;
    #pragma unroll
    for (int k = 0; k < 4; ++k) { int i = base + k; v[k] = (i < n) ? deg[i] : 0; s += v[k]; }
    sd[t] = s; __syncthreads();
    int mine = s;
    for (int off = 1; off < 256; off <<= 1) {
        int add = (t >= off) ? sd[t - off] : 0;
        __syncthreads();
        sd[t] += add;
        __syncthreads();
    }
    int run = sd[t] - mine + bsum[b];
    #pragma unroll
    for (int k = 0; k < 4; ++k) {
        int i = base + k;
        if (i < n) rowptr[i] = run;
        run += v[k];
    }
    if (b == 0 && t == 0) rowptr[n] = e;
}

__global__ void init_bcur(const int* __restrict__ rowptr, int* __restrict__ bcur) {
    int b = blockIdx.x * 256 + threadIdx.x;
    if (b < NBKT) bcur[b] = rowptr[b * 256];
}

// Pass A (two-level): per-block LDS histogram of the 391 buckets, one global
// atomicAdd per (block,bucket) to reserve a range, then LDS-cursor scatter.
// Packed entry: src (17b) | (dst&255) << 17.
__global__ __launch_bounds__(256) void bin_edges2(const int* __restrict__ ei,
        int* __restrict__ bcur, int* __restrict__ ebuf, int e) {
    __shared__ int hist[NBKT];
    __shared__ int base[NBKT];
    int t = threadIdx.x;
    int start = blockIdx.x * BIN_CHUNK;
    int end = start + BIN_CHUNK; if (end > e) end = e;
    for (int b = t; b < NBKT; b += 256) hist[b] = 0;
    __syncthreads();
    for (int i = start + t; i < end; i += 256)
        atomicAdd(&hist[ei[e + i] >> 8], 1);
    __syncthreads();
    for (int b = t; b < NBKT; b += 256) {
        int c = hist[b];
        base[b] = (c > 0) ? atomicAdd(&bcur[b], c) : 0;
        hist[b] = 0;
    }
    __syncthreads();
    for (int i = start + t; i < end; i += 256) {
        int d = ei[e + i], s = ei[i];
        int b = d >> 8;
        int pos = base[b] + atomicAdd(&hist[b], 1);
        ebuf[pos] = s | ((d & 255) << 17);
    }
}

// Pass B: one block per bucket; LDS cursors; colarr writes confined to the
// bucket's contiguous CSR region.
__global__ __launch_bounds__(256) void distribute(const int* __restrict__ ebuf,
        const int* __restrict__ rowptr, int* __restrict__ colarr, int n) {
    __shared__ int cur[256];
    int b = blockIdx.x, t = threadIdx.x;
    int n0 = b * 256;
    int n1 = n0 + 256; if (n1 > n) n1 = n;
    if (n0 + t < n1) cur[t] = rowptr[n0 + t];
    __syncthreads();
    int ebeg = rowptr[n0], eend = rowptr[n1];
    for (int i = ebeg + t; i < eend; i += 256) {
        int v = ebuf[i];
        int pos = atomicAdd(&cur[(v >> 17) & 255], 1);
        colarr[pos] = v & 0x1FFFF;
    }
}

// ---------------- weight pre-split (all 8 matrices, one launch) ----------------
// MFMA B-fragment layout: lane holds B[k=(lane>>4)*8+j][n=lane&15], j=0..7.
// Storage: [(kc*8+nt)*64 + lane]*8 + j. hi=bf16(W), lo=bf16(W-hi).

__global__ void wsplit_all(
        const float* __restrict__ w0, const float* __restrict__ w1,
        const float* __restrict__ w2, const float* __restrict__ w3,
        const float* __restrict__ w4, const float* __restrict__ w5,
        const float* __restrict__ w6, const float* __restrict__ w7,
        ushort* __restrict__ hiB, ushort* __restrict__ loB) {
    const float* ws[8] = {w0, w1, w2, w3, w4, w5, w6, w7};
    int gidx = blockIdx.x * 256 + threadIdx.x;   // 0..131071
    int mi = gidx >> 14;
    int idx = gidx & 16383;
    int j = idx & 7, l = (idx >> 3) & 63, blk = idx >> 9;
    int kc = blk >> 3, nt = blk & 7;
    int k = kc * 32 + (l >> 4) * 8 + j;
    int n = nt * 16 + (l & 15);
    float f = ws[mi][k * 128 + n];
    ushort h = f2bf(f);
    float hf = __uint_as_float((uint)h << 16);
    hiB[gidx] = h;
    loB[gidx] = f2bf(f - hf);
}

// ---------------- layer-0 aggregation (d=7) ----------------

__global__ __launch_bounds__(256) void agg7(const float* __restrict__ xin,
        const int* __restrict__ rowptr, const int* __restrict__ colarr,
        float* __restrict__ h0, int n) {
    int node = blockIdx.x * 32 + (threadIdx.x >> 3);
    int f = threadIdx.x & 7;
    if (node >= n) return;
    int fidx = (f < 7) ? f : 0;
    float acc = xin[node * 7 + fidx];
    int beg = rowptr[node], end = rowptr[node + 1];
    int j = beg;
    for (; j + 4 <= end; j += 4) {
        int s0 = colarr[j], s1 = colarr[j+1], s2 = colarr[j+2], s3 = colarr[j+3];
        float v0 = xin[s0*7 + fidx], v1 = xin[s1*7 + fidx];
        float v2 = xin[s2*7 + fidx], v3 = xin[s3*7 + fidx];
        acc += (v0 + v1) + (v2 + v3);
    }
    for (; j < end; ++j) acc += xin[colarr[j]*7 + fidx];
    h0[node * 8 + f] = (f < 7) ? acc : 0.f;
}

// ---------------- small first linear ----------------

__global__ __launch_bounds__(256) void lin7(const float* __restrict__ h0,
        const float* __restrict__ W, const float* __restrict__ bias,
        float* __restrict__ out, int n) {
    __shared__ float wl[7][128];
    __shared__ float hl[8][8];
    int t = threadIdx.x;
    for (int l = t; l < 7 * 128; l += 256) wl[l >> 7][l & 127] = W[l];
    int row0 = blockIdx.x * 8;
    if (t < 64) {
        int r = t >> 3, k = t & 7;
        int gr = row0 + r;
        hl[r][k] = (gr < n) ? h0[gr * 8 + k] : 0.f;
    }
    __syncthreads();
    int c = t & 127, g = t >> 7;
    float bv = bias[c];
    #pragma unroll
    for (int i = 0; i < 4; ++i) {
        int r = g * 4 + i, gr = row0 + r;
        if (gr < n) {
            float acc = bv;
            #pragma unroll
            for (int k = 0; k < 7; ++k) acc += hl[r][k] * wl[k][c];
            out[gr * 128 + c] = fmaxf(acc, 0.f);
        }
    }
}

// ------- fused [bf16 aggregate] + MFMA MLP + JK + pool (256 thr = 4 waves) -------

__device__ __forceinline__ int swz(int r) { return ((r >> 2) & 7) * 4; }

__device__ __forceinline__ void gemm_mfma(
        const ushort* __restrict__ WH, const ushort* __restrict__ WL,
        const float (&a_lds)[64][128], int mt, int lm, int lq, int l,
        f32x4 (&acc)[8])
{
    #pragma unroll
    for (int nt = 0; nt < 8; ++nt) acc[nt] = (f32x4){0.f, 0.f, 0.f, 0.f};
    const short8* BH = (const short8*)WH;
    const short8* BL = (const short8*)WL;
    int m = mt + lm;
    int s = swz(m);
    #pragma unroll
    for (int kc = 0; kc < 4; ++kc) {
        int cb = kc * 32 + lq * 8;
        float4 a0 = *(const float4*)&a_lds[m][cb ^ s];
        float4 a1 = *(const float4*)&a_lds[m][(cb + 4) ^ s];
        float av[8] = {a0.x, a0.y, a0.z, a0.w, a1.x, a1.y, a1.z, a1.w};
        short8 ah, al8;
        #pragma unroll
        for (int j = 0; j < 8; ++j) {
            ushort h = f2bf(av[j]);
            ah[j] = (short)h;
            float hf = __uint_as_float((uint)h << 16);
            al8[j] = (short)f2bf(av[j] - hf);
        }
        #pragma unroll
        for (int nt = 0; nt < 8; ++nt) {
            short8 bh = BH[(kc * 8 + nt) * 64 + l];
            short8 bl = BL[(kc * 8 + nt) * 64 + l];
            acc[nt] = __builtin_amdgcn_mfma_f32_16x16x32_bf16(ah,  bh, acc[nt], 0, 0, 0);
            acc[nt] = __builtin_amdgcn_mfma_f32_16x16x32_bf16(al8, bh, acc[nt], 0, 0, 0);
            acc[nt] = __builtin_amdgcn_mfma_f32_16x16x32_bf16(ah,  bl, acc[nt], 0, 0, 0);
        }
    }
}

__device__ __forceinline__ void epi_store(f32x4 (&acc)[8], const float* __restrict__ bias,
        float (&a_lds)[64][128], int row0, int n, int mt, int lm, int lq,
        ushort* __restrict__ xout)
{
    #pragma unroll
    for (int nt = 0; nt < 8; ++nt) {
        int col = nt * 16 + lm;
        float bv = bias[col];
        #pragma unroll
        for (int r = 0; r < 4; ++r) {
            int row = mt + lq * 4 + r;
            int gr = row0 + row;
            float v = fmaxf(acc[nt][r] + bv, 0.f);
            if (gr >= n) v = 0.f;
            a_lds[row][col ^ swz(row)] = v;
            if (xout != nullptr && gr < n)
                xout[(size_t)gr * 128 + col] = f2bf(v);
        }
    }
}

template<bool GATHER, bool DO_A, bool LASTB, bool WRITE_X>
__global__ __launch_bounds__(256) void mlp_fused(
        const float* __restrict__ in_f32, const ushort* __restrict__ in_bf,
        const int* __restrict__ rowptr, const int* __restrict__ colarr,
        const ushort* __restrict__ WaH, const ushort* __restrict__ WaL,
        const float* __restrict__ ba,
        const ushort* __restrict__ WbH, const ushort* __restrict__ WbL,
        const float* __restrict__ bb,
        const ushort* __restrict__ WjH, const ushort* __restrict__ WjL,
        const float* __restrict__ bjk,
        const int* __restrict__ batch,
        ushort* __restrict__ xout_bf, float* __restrict__ pooled, int n)
{
    __shared__ float a_lds[64][128];   // 32 KB
    int t = threadIdx.x;
    int row0 = blockIdx.x * 64;

    if (GATHER) {
        // Edge-balanced gather: block time tracks MEAN degree, not max.
        // a_lds doubles as the fp32 accumulator (self-term pre-init, no atomics),
        // then each 4-thread group walks an equal slice of the block's dst-sorted
        // CSR window, accumulating per-dst runs in registers and flushing to LDS
        // with ds_add_f32 atomics on row change (~2-3 flushes/group).
        __shared__ int rp[65];          // window rowptr (relative to eb)
        int rlast = row0 + 64; if (rlast > n) rlast = n;
        int nrows = rlast - row0;
        int eb = rowptr[row0];
        if (t < 65) {
            int i = t < nrows ? t : nrows;
            rp[t] = rowptr[row0 + i] - eb;
        }
        // self-term init (unique writes, fp32, swizzled)
        int r = t >> 2, q = t & 3;
        int gr = row0 + r;
        {
            int s = swz(r);
            #pragma unroll
            for (int i = 0; i < 4; ++i) {
                float4 lo4 = make_float4(0.f, 0.f, 0.f, 0.f);
                float4 hi4 = make_float4(0.f, 0.f, 0.f, 0.f);
                if (gr < n) {
                    uint4 v = ((const uint4*)(in_bf + (size_t)gr * 128))[i * 4 + q];
                    lo4 = make_float4(bflo(v.x), bfhi(v.x), bflo(v.y), bfhi(v.y));
                    hi4 = make_float4(bflo(v.z), bfhi(v.z), bflo(v.w), bfhi(v.w));
                }
                int c = (i * 4 + q) * 8;
                *(float4*)&a_lds[r][c ^ s]       = lo4;
                *(float4*)&a_lds[r][(c + 4) ^ s] = hi4;
            }
        }
        __syncthreads();

        int cnt = rp[64];               // == rowptr[rlast] - eb
        int g = t >> 2;                 // group 0..63
        int e0 = (int)(((long long)cnt * g) >> 6);
        int e1 = (int)(((long long)cnt * (g + 1)) >> 6);
        if (e1 > e0) {
            // find row with rp[row] <= e0 < rp[row+1]
            int lo = 0, hi = nrows - 1;
            while (lo < hi) {
                int mid = (lo + hi) >> 1;
                if (rp[mid + 1] <= e0) lo = mid + 1; else hi = mid;
            }
            int row = lo;
            float fa[4][8];
            #pragma unroll
            for (int i = 0; i < 4; ++i)
                #pragma unroll
                for (int k = 0; k < 8; ++k) fa[i][k] = 0.f;
            bool dirty = false;
            for (int j = e0; j < e1; ++j) {
                while (j >= rp[row + 1]) {
                    if (dirty) {
                        int s2 = swz(row);
                        #pragma unroll
                        for (int i = 0; i < 4; ++i) {
                            int c = (i * 4 + q) * 8;
                            #pragma unroll
                            for (int k = 0; k < 8; ++k)
                                atomicAdd(&a_lds[row][(c + k) ^ s2], fa[i][k]);
                        }
                        #pragma unroll
                        for (int i = 0; i < 4; ++i)
                            #pragma unroll
                            for (int k = 0; k < 8; ++k) fa[i][k] = 0.f;
                        dirty = false;
                    }
                    ++row;
                }
                int src = colarr[eb + j];
                const uint4* np = (const uint4*)(in_bf + (size_t)src * 128);
                #pragma unroll
                for (int i = 0; i < 4; ++i) {
                    uint4 v = np[i * 4 + q];
                    fa[i][0] += bflo(v.x); fa[i][1] += bfhi(v.x);
                    fa[i][2] += bflo(v.y); fa[i][3] += bfhi(v.y);
                    fa[i][4] += bflo(v.z); fa[i][5] += bfhi(v.z);
                    fa[i][6] += bflo(v.w); fa[i][7] += bfhi(v.w);
                }
                dirty = true;
            }
            if (dirty) {
                int s2 = swz(row);
                #pragma unroll
                for (int i = 0; i < 4; ++i) {
                    int c = (i * 4 + q) * 8;
                    #pragma unroll
                    for (int k = 0; k < 8; ++k)
                        atomicAdd(&a_lds[row][(c + k) ^ s2], fa[i][k]);
                }
            }
        }
    } else {
        #pragma unroll
        for (int it = 0; it < 8; ++it) {
            int l = t + 256 * it;
            int r = l >> 5, c4 = (l & 31) * 4;
            int gr = row0 + r;
            float4 av = make_float4(0.f, 0.f, 0.f, 0.f);
            if (gr < n) av = *(const float4*)&in_f32[gr * 128 + c4];
            *(float4*)&a_lds[r][c4 ^ swz(r)] = av;
        }
    }
    __syncthreads();

    int w = t >> 6, l = t & 63;
    int mt = w * 16, lm = l & 15, lq = l >> 4;
    f32x4 acc[8];

    if (DO_A) {
        gemm_mfma(WaH, WaL, a_lds, mt, lm, lq, l, acc);
        __syncthreads();
        epi_store(acc, ba, a_lds, row0, n, mt, lm, lq, nullptr);
        __syncthreads();
    }

    gemm_mfma(WbH, WbL, a_lds, mt, lm, lq, l, acc);
    __syncthreads();
    epi_store(acc, bb, a_lds, row0, n, mt, lm, lq, WRITE_X ? xout_bf : nullptr);
    __syncthreads();

    gemm_mfma(WjH, WjL, a_lds, mt, lm, lq, l, acc);
    __syncthreads();

    // JK epilogue: +bjk (last layer), mask invalid rows, stage y into a_lds
    #pragma unroll
    for (int nt = 0; nt < 8; ++nt) {
        int col = nt * 16 + lm;
        float bv = LASTB ? bjk[col] : 0.f;
        #pragma unroll
        for (int r = 0; r < 4; ++r) {
            int row = mt + lq * 4 + r;
            int gr = row0 + row;
            float v = acc[nt][r] + bv;
            if (gr >= n) v = 0.f;
            a_lds[row][col ^ swz(row)] = v;
        }
    }
    __syncthreads();

    // pooling
    int row_last = row0 + 63; if (row_last > n - 1) row_last = n - 1;
    int g_first = batch[row0];
    int g_last  = batch[row_last];
    int c = t & 127, half = t >> 7;
    if (g_first == g_last) {
        float sacc = 0.f;
        for (int r = half * 32; r < half * 32 + 32; ++r)
            sacc += a_lds[r][c ^ swz(r)];
        __syncthreads();
        a_lds[half][c] = sacc;
        __syncthreads();
        if (t < 128)
            atomicAdd(&pooled[g_first * 128 + t], a_lds[0][t] + a_lds[1][t]);
    } else {
        float sacc = 0.f; int gprev = -1;
        for (int r = half * 32; r < half * 32 + 32; ++r) {
            int gr = row0 + r;
            if (gr >= n) break;
            int g = batch[gr];
            if (g != gprev) {
                if (gprev >= 0) atomicAdd(&pooled[gprev * 128 + c], sacc);
                sacc = 0.f; gprev = g;
            }
            sacc += a_lds[r][c ^ swz(r)];
        }
        if (gprev >= 0) atomicAdd(&pooled[gprev * 128 + c], sacc);
    }
}

// ---------------- classifier ----------------

__global__ __launch_bounds__(256) void classifier(const float* __restrict__ pooled,
        const float* __restrict__ Wc1, const float* __restrict__ bc1,
        const float* __restrict__ gamma, const float* __restrict__ beta,
        const float* __restrict__ rmean, const float* __restrict__ rvar,
        const float* __restrict__ Wc2, const float* __restrict__ bc2,
        float* __restrict__ out) {
    int g = blockIdx.x, t = threadIdx.x;
    __shared__ float p[128];
    __shared__ float r0[256], r1[256];
    if (t < 128) p[t] = pooled[g * 128 + t];
    __syncthreads();
    float acc = bc1[t];
    #pragma unroll 8
    for (int k = 0; k < 128; ++k) acc += p[k] * Wc1[k * 256 + t];
    float z = (acc - rmean[t]) * rsqrtf(rvar[t] + 1e-5f) * gamma[t] + beta[t];
    z = fmaxf(z, 0.f);
    r0[t] = z * Wc2[t * 2 + 0];
    r1[t] = z * Wc2[t * 2 + 1];
    __syncthreads();
    for (int s = 128; s > 0; s >>= 1) {
        if (t < s) { r0[t] += r0[t + s]; r1[t] += r1[t + s]; }
        __syncthreads();
    }
    if (t == 0) {
        out[g * 2 + 0] = r0[0] + bc2[0];
        out[g * 2 + 1] = r1[0] + bc2[1];
    }
}

// ---------------- launch ----------------

static inline size_t al256(size_t x) { return (x + 255) & ~size_t(255); }

extern "C" void kernel_launch(void* const* d_in, const int* in_sizes, int n_in,
                              void* d_out, int out_size, void* d_ws, size_t ws_size,
                              hipStream_t stream) {
    const float* x    = (const float*)d_in[0];
    const int*   ei   = (const int*)  d_in[1];
    const int*   batch= (const int*)  d_in[3];
    const float* W0a = (const float*)d_in[4];  const float* b0a = (const float*)d_in[5];
    const float* W0b = (const float*)d_in[6];  const float* b0b = (const float*)d_in[7];
    const float* W1a = (const float*)d_in[8];  const float* b1a = (const float*)d_in[9];
    const float* W1b = (const float*)d_in[10]; const float* b1b = (const float*)d_in[11];
    const float* W2a = (const float*)d_in[12]; const float* b2a = (const float*)d_in[13];
    const float* W2b = (const float*)d_in[14]; const float* b2b = (const float*)d_in[15];
    const float* Wjk = (const float*)d_in[16]; const float* bjk = (const float*)d_in[17];
    const float* Wc1 = (const float*)d_in[18]; const float* bc1 = (const float*)d_in[19];
    const float* gamma=(const float*)d_in[20]; const float* beta= (const float*)d_in[21];
    const float* rmean=(const float*)d_in[22]; const float* rvar= (const float*)d_in[23];
    const float* Wc2 = (const float*)d_in[24]; const float* bc2 = (const float*)d_in[25];
    float* out = (float*)d_out;

    const int N = NN, E = EE, B = BB;

    char* w = (char*)d_ws;
    size_t off = 0;
    int* deg    = (int*)(w + off); off = al256(off + (size_t)N * 4);
    int* rowptr = (int*)(w + off); off = al256(off + (size_t)(N + 1) * 4);
    int* bcur   = (int*)(w + off); off = al256(off + (size_t)NBKT * 4);
    int* colarr = (int*)(w + off); off = al256(off + (size_t)E * 4);
    int* ebuf   = (int*)(w + off); off = al256(off + (size_t)E * 4);
    int* bsum   = (int*)(w + off); off = al256(off + 1024 * 4);
    float* h0   = (float*)(w + off); off = al256(off + (size_t)N * 8 * 4);
    float* SB   = (float*)(w + off); off = al256(off + (size_t)N * 128 * 4);
    ushort* XB1 = (ushort*)(w + off); off = al256(off + (size_t)N * 128 * 2);
    ushort* XB2 = (ushort*)(w + off); off = al256(off + (size_t)N * 128 * 2);
    float* pooled = (float*)(w + off); off = al256(off + (size_t)B * 128 * 4);
    ushort* wfH = (ushort*)(w + off); off = al256(off + (size_t)8 * 16384 * 2);
    ushort* wfL = (ushort*)(w + off); off = al256(off + (size_t)8 * 16384 * 2);

    hipMemsetAsync(deg, 0, (size_t)N * 4, stream);
    hipMemsetAsync(pooled, 0, (size_t)B * 128 * 4, stream);

    // pre-split weights (order: W0b, W1a, W1b, W2a, W2b, Wjk0, Wjk1, Wjk2)
    wsplit_all<<<512, 256, 0, stream>>>(W0b, W1a, W1b, W2a, W2b,
                                        Wjk, Wjk + 128 * 128, Wjk + 256 * 128,
                                        wfH, wfL);

    int nb = (N + 1023) / 1024;   // 98

    count_deg<<<(E + 255) / 256, 256, 0, stream>>>(ei, deg, E);
    scan_partial<<<nb, 256, 0, stream>>>(deg, bsum, N);
    scan_bsum<<<1, 256, 0, stream>>>(bsum, nb);
    scan_apply<<<nb, 256, 0, stream>>>(deg, bsum, rowptr, N, E);
    init_bcur<<<(NBKT + 255) / 256, 256, 0, stream>>>(rowptr, bcur);
    bin_edges2<<<(E + BIN_CHUNK - 1) / BIN_CHUNK, 256, 0, stream>>>(ei, bcur, ebuf, E);
    distribute<<<NBKT, 256, 0, stream>>>(ebuf, rowptr, colarr, N);

    int gLin = (N + 63) / 64;   // 1563

    // Layer 0: agg7 -> lin7 -> mlp0, x1 -> XB1 (bf16)
    agg7<<<(N + 31) / 32, 256, 0, stream>>>(x, rowptr, colarr, h0, N);
    lin7<<<(N + 7) / 8, 256, 0, stream>>>(h0, W0a, b0a, SB, N);
    mlp_fused<false, false, false, true><<<gLin, 256, 0, stream>>>(
        SB, nullptr, rowptr, colarr,
        nullptr, nullptr, nullptr,
        wfH + 0 * 16384, wfL + 0 * 16384, b0b,
        wfH + 5 * 16384, wfL + 5 * 16384, nullptr,
        batch, XB1, pooled, N);

    // Layer 1: bf16 gather XB1 -> MLP -> x2 -> XB2 (bf16)
    mlp_fused<true, true, false, true><<<gLin, 256, 0, stream>>>(
        nullptr, XB1, rowptr, colarr,
        wfH + 1 * 16384, wfL + 1 * 16384, b1a,
        wfH + 2 * 16384, wfL + 2 * 16384, b1b,
        wfH + 6 * 16384, wfL + 6 * 16384, nullptr,
        batch, XB2, pooled, N);

    // Layer 2: bf16 gather XB2 -> MLP -> jk2 (x3 never materialized)
    mlp_fused<true, true, true, false><<<gLin, 256, 0, stream>>>(
        nullptr, XB2, rowptr, colarr,
        wfH + 3 * 16384, wfL + 3 * 16384, b2a,
        wfH + 4 * 16384, wfL + 4 * 16384, b2b,
        wfH + 7 * 16384, wfL + 7 * 16384, bjk,
        batch, nullptr, pooled, N);

    classifier<<<B, 256, 0, stream>>>(pooled, Wc1, bc1, gamma, beta,
                                      rmean, rvar, Wc2, bc2, out);
}

// Round 14
// 672.911 us; speedup vs baseline: 1.1324x; 1.1324x over previous
//
#include <hip/hip_runtime.h>

#define NN 100000
#define EE 1600000
#define BB 256
#define IN_F 7
#define HH 128
#define NBKT 391        // ceil(NN/256) buckets for binned CSR fill
#define BIN_CHUNK 4096  // edges per bin_edges2 block

typedef unsigned int uint;
typedef unsigned short ushort;
typedef __attribute__((ext_vector_type(8))) short short8;
typedef __attribute__((ext_vector_type(4))) float f32x4;

// ---------------- bf16 helpers ----------------

__device__ __forceinline__ float bflo(uint u) { return __uint_as_float(u << 16); }
__device__ __forceinline__ float bfhi(uint u) { return __uint_as_float(u & 0xFFFF0000u); }
__device__ __forceinline__ ushort f2bf(float x) {   // RNE; inputs finite
    uint u = __float_as_uint(x);
    u = (u + 0x7FFFu + ((u >> 16) & 1u)) >> 16;
    return (ushort)u;
}

// ---------------- CSR build ----------------

__global__ void count_deg(const int* __restrict__ ei, int* __restrict__ deg, int e) {
    int i = blockIdx.x * 256 + threadIdx.x;
    if (i < e) atomicAdd(&deg[ei[e + i]], 1);   // dst = ei[E + i]
}

__global__ void scan_partial(const int* __restrict__ deg, int* __restrict__ bsum, int n) {
    __shared__ int sd[256];
    int b = blockIdx.x, t = threadIdx.x;
    int base = b * 1024 + t * 4;
    int s = 0;
    #pragma unroll
    for (int k = 0; k < 4; ++k) { int i = base + k; if (i < n) s += deg[i]; }
    sd[t] = s; __syncthreads();
    for (int off = 128; off > 0; off >>= 1) {
        if (t < off) sd[t] += sd[t + off];
        __syncthreads();
    }
    if (t == 0) bsum[b] = sd[0];
}

__global__ void scan_bsum(int* __restrict__ bsum, int nb) {
    __shared__ int sd[256];
    int t = threadIdx.x;
    int v = (t < nb) ? bsum[t] : 0;
    sd[t] = v; __syncthreads();
    for (int off = 1; off < 256; off <<= 1) {
        int add = (t >= off) ? sd[t - off] : 0;
        __syncthreads();
        sd[t] += add;
        __syncthreads();
    }
    if (t < nb) bsum[t] = sd[t] - v;   // exclusive
}

__global__ void scan_apply(const int* __restrict__ deg, const int* __restrict__ bsum,
                           int* __restrict__ rowptr, int n, int e) {
    __shared__ int sd[256];
    int b = blockIdx.x, t = threadIdx.x;
    int base = b * 1024 + t * 4;
    int v[4]; int s = 0;
    #pragma unroll
    for (int k = 0; k < 4; ++k) { int i = base + k; v[k] = (i < n) ? deg[i] : 0; s += v[k]; }
    sd[t] = s; __syncthreads();
    int mine = s;
    for (int off = 1; off < 256; off <<= 1) {
        int add = (t >= off) ? sd[t - off] : 0;
        __syncthreads();
        sd[t] += add;
        __syncthreads();
    }
    int run = sd[t] - mine + bsum[b];
    #pragma unroll
    for (int k = 0; k < 4; ++k) {
        int i = base + k;
        if (i < n) rowptr[i] = run;
        run += v[k];
    }
    if (b == 0 && t == 0) rowptr[n] = e;
}

__global__ void init_bcur(const int* __restrict__ rowptr, int* __restrict__ bcur) {
    int b = blockIdx.x * 256 + threadIdx.x;
    if (b < NBKT) bcur[b] = rowptr[b * 256];
}

// Pass A (two-level): per-block LDS histogram of the 391 buckets, one global
// atomicAdd per (block,bucket) to reserve a range, then LDS-cursor scatter.
// Packed entry: src (17b) | (dst&255) << 17.
__global__ __launch_bounds__(256) void bin_edges2(const int* __restrict__ ei,
        int* __restrict__ bcur, int* __restrict__ ebuf, int e) {
    __shared__ int hist[NBKT];
    __shared__ int base[NBKT];
    int t = threadIdx.x;
    int start = blockIdx.x * BIN_CHUNK;
    int end = start + BIN_CHUNK; if (end > e) end = e;
    for (int b = t; b < NBKT; b += 256) hist[b] = 0;
    __syncthreads();
    for (int i = start + t; i < end; i += 256)
        atomicAdd(&hist[ei[e + i] >> 8], 1);
    __syncthreads();
    for (int b = t; b < NBKT; b += 256) {
        int c = hist[b];
        base[b] = (c > 0) ? atomicAdd(&bcur[b], c) : 0;
        hist[b] = 0;
    }
    __syncthreads();
    for (int i = start + t; i < end; i += 256) {
        int d = ei[e + i], s = ei[i];
        int b = d >> 8;
        int pos = base[b] + atomicAdd(&hist[b], 1);
        ebuf[pos] = s | ((d & 255) << 17);
    }
}

// Pass B: one block per bucket; LDS cursors; colarr writes confined to the
// bucket's contiguous CSR region.
__global__ __launch_bounds__(256) void distribute(const int* __restrict__ ebuf,
        const int* __restrict__ rowptr, int* __restrict__ colarr, int n) {
    __shared__ int cur[256];
    int b = blockIdx.x, t = threadIdx.x;
    int n0 = b * 256;
    int n1 = n0 + 256; if (n1 > n) n1 = n;
    if (n0 + t < n1) cur[t] = rowptr[n0 + t];
    __syncthreads();
    int ebeg = rowptr[n0], eend = rowptr[n1];
    for (int i = ebeg + t; i < eend; i += 256) {
        int v = ebuf[i];
        int pos = atomicAdd(&cur[(v >> 17) & 255], 1);
        colarr[pos] = v & 0x1FFFF;
    }
}

// ---------------- weight pre-split (all 8 matrices, one launch) ----------------
// MFMA B-fragment layout: lane holds B[k=(lane>>4)*8+j][n=lane&15], j=0..7.
// Storage: [(kc*8+nt)*64 + lane]*8 + j. hi=bf16(W), lo=bf16(W-hi).

__global__ void wsplit_all(
        const float* __restrict__ w0, const float* __restrict__ w1,
        const float* __restrict__ w2, const float* __restrict__ w3,
        const float* __restrict__ w4, const float* __restrict__ w5,
        const float* __restrict__ w6, const float* __restrict__ w7,
        ushort* __restrict__ hiB, ushort* __restrict__ loB) {
    const float* ws[8] = {w0, w1, w2, w3, w4, w5, w6, w7};
    int gidx = blockIdx.x * 256 + threadIdx.x;   // 0..131071
    int mi = gidx >> 14;
    int idx = gidx & 16383;
    int j = idx & 7, l = (idx >> 3) & 63, blk = idx >> 9;
    int kc = blk >> 3, nt = blk & 7;
    int k = kc * 32 + (l >> 4) * 8 + j;
    int n = nt * 16 + (l & 15);
    float f = ws[mi][k * 128 + n];
    ushort h = f2bf(f);
    float hf = __uint_as_float((uint)h << 16);
    hiB[gidx] = h;
    loB[gidx] = f2bf(f - hf);
}

// ---------------- layer-0 aggregation (d=7) ----------------

__global__ __launch_bounds__(256) void agg7(const float* __restrict__ xin,
        const int* __restrict__ rowptr, const int* __restrict__ colarr,
        float* __restrict__ h0, int n) {
    int node = blockIdx.x * 32 + (threadIdx.x >> 3);
    int f = threadIdx.x & 7;
    if (node >= n) return;
    int fidx = (f < 7) ? f : 0;
    float acc = xin[node * 7 + fidx];
    int beg = rowptr[node], end = rowptr[node + 1];
    int j = beg;
    for (; j + 4 <= end; j += 4) {
        int s0 = colarr[j], s1 = colarr[j+1], s2 = colarr[j+2], s3 = colarr[j+3];
        float v0 = xin[s0*7 + fidx], v1 = xin[s1*7 + fidx];
        float v2 = xin[s2*7 + fidx], v3 = xin[s3*7 + fidx];
        acc += (v0 + v1) + (v2 + v3);
    }
    for (; j < end; ++j) acc += xin[colarr[j]*7 + fidx];
    h0[node * 8 + f] = (f < 7) ? acc : 0.f;
}

// ---------------- small first linear (bf16 output) ----------------

__global__ __launch_bounds__(256) void lin7(const float* __restrict__ h0,
        const float* __restrict__ W, const float* __restrict__ bias,
        ushort* __restrict__ out, int n) {
    __shared__ float wl[7][128];
    __shared__ float hl[8][8];
    int t = threadIdx.x;
    for (int l = t; l < 7 * 128; l += 256) wl[l >> 7][l & 127] = W[l];
    int row0 = blockIdx.x * 8;
    if (t < 64) {
        int r = t >> 3, k = t & 7;
        int gr = row0 + r;
        hl[r][k] = (gr < n) ? h0[gr * 8 + k] : 0.f;
    }
    __syncthreads();
    int c = t & 127, g = t >> 7;
    float bv = bias[c];
    #pragma unroll
    for (int i = 0; i < 4; ++i) {
        int r = g * 4 + i, gr = row0 + r;
        if (gr < n) {
            float acc = bv;
            #pragma unroll
            for (int k = 0; k < 7; ++k) acc += hl[r][k] * wl[k][c];
            out[gr * 128 + c] = f2bf(fmaxf(acc, 0.f));
        }
    }
}

// ------- fused [bf16 aggregate] + MFMA MLP + JK + pool (256 thr = 4 waves) -------

__device__ __forceinline__ int swz(int r) { return ((r >> 2) & 7) * 4; }

__device__ __forceinline__ void gemm_mfma(
        const ushort* __restrict__ WH, const ushort* __restrict__ WL,
        const float (&a_lds)[64][128], int mt, int lm, int lq, int l,
        f32x4 (&acc)[8])
{
    #pragma unroll
    for (int nt = 0; nt < 8; ++nt) acc[nt] = (f32x4){0.f, 0.f, 0.f, 0.f};
    const short8* BH = (const short8*)WH;
    const short8* BL = (const short8*)WL;
    int m = mt + lm;
    int s = swz(m);
    #pragma unroll
    for (int kc = 0; kc < 4; ++kc) {
        int cb = kc * 32 + lq * 8;
        float4 a0 = *(const float4*)&a_lds[m][cb ^ s];
        float4 a1 = *(const float4*)&a_lds[m][(cb + 4) ^ s];
        float av[8] = {a0.x, a0.y, a0.z, a0.w, a1.x, a1.y, a1.z, a1.w};
        short8 ah, al8;
        #pragma unroll
        for (int j = 0; j < 8; ++j) {
            ushort h = f2bf(av[j]);
            ah[j] = (short)h;
            float hf = __uint_as_float((uint)h << 16);
            al8[j] = (short)f2bf(av[j] - hf);
        }
        #pragma unroll
        for (int nt = 0; nt < 8; ++nt) {
            short8 bh = BH[(kc * 8 + nt) * 64 + l];
            short8 bl = BL[(kc * 8 + nt) * 64 + l];
            acc[nt] = __builtin_amdgcn_mfma_f32_16x16x32_bf16(ah,  bh, acc[nt], 0, 0, 0);
            acc[nt] = __builtin_amdgcn_mfma_f32_16x16x32_bf16(al8, bh, acc[nt], 0, 0, 0);
            acc[nt] = __builtin_amdgcn_mfma_f32_16x16x32_bf16(ah,  bl, acc[nt], 0, 0, 0);
        }
    }
}

__device__ __forceinline__ void epi_store(f32x4 (&acc)[8], const float* __restrict__ bias,
        float (&a_lds)[64][128], int row0, int n, int mt, int lm, int lq,
        ushort* __restrict__ xout)
{
    #pragma unroll
    for (int nt = 0; nt < 8; ++nt) {
        int col = nt * 16 + lm;
        float bv = bias[col];
        #pragma unroll
        for (int r = 0; r < 4; ++r) {
            int row = mt + lq * 4 + r;
            int gr = row0 + row;
            float v = fmaxf(acc[nt][r] + bv, 0.f);
            if (gr >= n) v = 0.f;
            a_lds[row][col ^ swz(row)] = v;
            if (xout != nullptr && gr < n)
                xout[(size_t)gr * 128 + col] = f2bf(v);
        }
    }
}

template<bool GATHER, bool DO_A, bool LASTB, bool WRITE_X>
__global__ __launch_bounds__(256) void mlp_fused(
        const ushort* __restrict__ in_bf,
        const int* __restrict__ rowptr, const int* __restrict__ colarr,
        const ushort* __restrict__ WaH, const ushort* __restrict__ WaL,
        const float* __restrict__ ba,
        const ushort* __restrict__ WbH, const ushort* __restrict__ WbL,
        const float* __restrict__ bb,
        const ushort* __restrict__ WjH, const ushort* __restrict__ WjL,
        const float* __restrict__ bjk,
        const int* __restrict__ batch,
        ushort* __restrict__ xout_bf, float* __restrict__ pooled, int n)
{
    __shared__ float a_lds[64][128];   // 32 KB
    int t = threadIdx.x;
    int row0 = blockIdx.x * 64;

    if (GATHER) {
        // Stage this block's edge-index window into a_lds (reused as int scratch;
        // gather results stay in registers until after the barrier).
        int* idx_lds = (int*)&a_lds[0][0];      // capacity 8192 ints
        int rlast = row0 + 64; if (rlast > n) rlast = n;
        int eb = rowptr[row0];
        int cnt = rowptr[rlast] - eb;
        int staged = cnt < 8192 ? cnt : 8192;
        for (int i = t; i < staged; i += 256) idx_lds[i] = colarr[eb + i];
        __syncthreads();

        int r = t >> 2, q = t & 3;
        int gr = row0 + r;
        float f[4][8];
        #pragma unroll
        for (int i = 0; i < 4; ++i)
            #pragma unroll
            for (int j = 0; j < 8; ++j) f[i][j] = 0.f;
        if (gr < n) {
            const uint4* sp = (const uint4*)(in_bf + (size_t)gr * 128);
            #pragma unroll
            for (int i = 0; i < 4; ++i) {
                uint4 v = sp[i * 4 + q];
                f[i][0] = bflo(v.x); f[i][1] = bfhi(v.x);
                f[i][2] = bflo(v.y); f[i][3] = bfhi(v.y);
                f[i][4] = bflo(v.z); f[i][5] = bfhi(v.z);
                f[i][6] = bflo(v.w); f[i][7] = bfhi(v.w);
            }
            int beg = rowptr[gr] - eb, end = rowptr[gr + 1] - eb;
            int j = beg;
            // x4 neighbor unroll: 16 outstanding uint4 loads per thread (MLP).
            for (; j + 4 <= end; j += 4) {
                int s0 = (j     < staged) ? idx_lds[j]     : colarr[eb + j];
                int s1 = (j + 1 < staged) ? idx_lds[j + 1] : colarr[eb + j + 1];
                int s2 = (j + 2 < staged) ? idx_lds[j + 2] : colarr[eb + j + 2];
                int s3 = (j + 3 < staged) ? idx_lds[j + 3] : colarr[eb + j + 3];
                const uint4* n0 = (const uint4*)(in_bf + (size_t)s0 * 128);
                const uint4* n1 = (const uint4*)(in_bf + (size_t)s1 * 128);
                const uint4* n2 = (const uint4*)(in_bf + (size_t)s2 * 128);
                const uint4* n3 = (const uint4*)(in_bf + (size_t)s3 * 128);
                uint4 v0[4], v1[4], v2[4], v3[4];
                #pragma unroll
                for (int i = 0; i < 4; ++i) {
                    v0[i] = n0[i * 4 + q]; v1[i] = n1[i * 4 + q];
                    v2[i] = n2[i * 4 + q]; v3[i] = n3[i * 4 + q];
                }
                #pragma unroll
                for (int i = 0; i < 4; ++i) {
                    f[i][0] += (bflo(v0[i].x) + bflo(v1[i].x)) + (bflo(v2[i].x) + bflo(v3[i].x));
                    f[i][1] += (bfhi(v0[i].x) + bfhi(v1[i].x)) + (bfhi(v2[i].x) + bfhi(v3[i].x));
                    f[i][2] += (bflo(v0[i].y) + bflo(v1[i].y)) + (bflo(v2[i].y) + bflo(v3[i].y));
                    f[i][3] += (bfhi(v0[i].y) + bfhi(v1[i].y)) + (bfhi(v2[i].y) + bfhi(v3[i].y));
                    f[i][4] += (bflo(v0[i].z) + bflo(v1[i].z)) + (bflo(v2[i].z) + bflo(v3[i].z));
                    f[i][5] += (bfhi(v0[i].z) + bfhi(v1[i].z)) + (bfhi(v2[i].z) + bfhi(v3[i].z));
                    f[i][6] += (bflo(v0[i].w) + bflo(v1[i].w)) + (bflo(v2[i].w) + bflo(v3[i].w));
                    f[i][7] += (bfhi(v0[i].w) + bfhi(v1[i].w)) + (bfhi(v2[i].w) + bfhi(v3[i].w));
                }
            }
            for (; j < end; ++j) {
                int s0 = (j < staged) ? idx_lds[j] : colarr[eb + j];
                const uint4* np = (const uint4*)(in_bf + (size_t)s0 * 128);
                #pragma unroll
                for (int i = 0; i < 4; ++i) {
                    uint4 v = np[i * 4 + q];
                    f[i][0] += bflo(v.x); f[i][1] += bfhi(v.x);
                    f[i][2] += bflo(v.y); f[i][3] += bfhi(v.y);
                    f[i][4] += bflo(v.z); f[i][5] += bfhi(v.z);
                    f[i][6] += bflo(v.w); f[i][7] += bfhi(v.w);
                }
            }
        }
        __syncthreads();   // all idx_lds reads done before a_lds is overwritten
        int s = swz(r);
        #pragma unroll
        for (int i = 0; i < 4; ++i) {
            int c = (i * 4 + q) * 8;
            *(float4*)&a_lds[r][c ^ s]       = make_float4(f[i][0], f[i][1], f[i][2], f[i][3]);
            *(float4*)&a_lds[r][(c + 4) ^ s] = make_float4(f[i][4], f[i][5], f[i][6], f[i][7]);
        }
    } else {
        // bf16 staging of t0 (no gather): 1024 uint4 = 64 rows x 16 chunks
        #pragma unroll
        for (int it = 0; it < 4; ++it) {
            int l = t + 256 * it;
            int r = l >> 4, c8 = (l & 15) * 8;
            int gr = row0 + r;
            uint4 v = make_uint4(0u, 0u, 0u, 0u);
            if (gr < n) v = *(const uint4*)&in_bf[(size_t)gr * 128 + c8];
            int s = swz(r);
            *(float4*)&a_lds[r][c8 ^ s] =
                make_float4(bflo(v.x), bfhi(v.x), bflo(v.y), bfhi(v.y));
            *(float4*)&a_lds[r][(c8 + 4) ^ s] =
                make_float4(bflo(v.z), bfhi(v.z), bflo(v.w), bfhi(v.w));
        }
    }
    __syncthreads();

    int w = t >> 6, l = t & 63;
    int mt = w * 16, lm = l & 15, lq = l >> 4;
    f32x4 acc[8];

    if (DO_A) {
        gemm_mfma(WaH, WaL, a_lds, mt, lm, lq, l, acc);
        __syncthreads();
        epi_store(acc, ba, a_lds, row0, n, mt, lm, lq, nullptr);
        __syncthreads();
    }

    gemm_mfma(WbH, WbL, a_lds, mt, lm, lq, l, acc);
    __syncthreads();
    epi_store(acc, bb, a_lds, row0, n, mt, lm, lq, WRITE_X ? xout_bf : nullptr);
    __syncthreads();

    gemm_mfma(WjH, WjL, a_lds, mt, lm, lq, l, acc);
    __syncthreads();

    // JK epilogue: +bjk (last layer), mask invalid rows, stage y into a_lds
    #pragma unroll
    for (int nt = 0; nt < 8; ++nt) {
        int col = nt * 16 + lm;
        float bv = LASTB ? bjk[col] : 0.f;
        #pragma unroll
        for (int r = 0; r < 4; ++r) {
            int row = mt + lq * 4 + r;
            int gr = row0 + row;
            float v = acc[nt][r] + bv;
            if (gr >= n) v = 0.f;
            a_lds[row][col ^ swz(row)] = v;
        }
    }
    __syncthreads();

    // pooling
    int row_last = row0 + 63; if (row_last > n - 1) row_last = n - 1;
    int g_first = batch[row0];
    int g_last  = batch[row_last];
    int c = t & 127, half = t >> 7;
    if (g_first == g_last) {
        float sacc = 0.f;
        for (int r = half * 32; r < half * 32 + 32; ++r)
            sacc += a_lds[r][c ^ swz(r)];
        __syncthreads();
        a_lds[half][c] = sacc;
        __syncthreads();
        if (t < 128)
            atomicAdd(&pooled[g_first * 128 + t], a_lds[0][t] + a_lds[1][t]);
    } else {
        float sacc = 0.f; int gprev = -1;
        for (int r = half * 32; r < half * 32 + 32; ++r) {
            int gr = row0 + r;
            if (gr >= n) break;
            int g = batch[gr];
            if (g != gprev) {
                if (gprev >= 0) atomicAdd(&pooled[gprev * 128 + c], sacc);
                sacc = 0.f; gprev = g;
            }
            sacc += a_lds[r][c ^ swz(r)];
        }
        if (gprev >= 0) atomicAdd(&pooled[gprev * 128 + c], sacc);
    }
}

// ---------------- classifier ----------------

__global__ __launch_bounds__(256) void classifier(const float* __restrict__ pooled,
        const float* __restrict__ Wc1, const float* __restrict__ bc1,
        const float* __restrict__ gamma, const float* __restrict__ beta,
        const float* __restrict__ rmean, const float* __restrict__ rvar,
        const float* __restrict__ Wc2, const float* __restrict__ bc2,
        float* __restrict__ out) {
    int g = blockIdx.x, t = threadIdx.x;
    __shared__ float p[128];
    __shared__ float r0[256], r1[256];
    if (t < 128) p[t] = pooled[g * 128 + t];
    __syncthreads();
    float acc = bc1[t];
    #pragma unroll 8
    for (int k = 0; k < 128; ++k) acc += p[k] * Wc1[k * 256 + t];
    float z = (acc - rmean[t]) * rsqrtf(rvar[t] + 1e-5f) * gamma[t] + beta[t];
    z = fmaxf(z, 0.f);
    r0[t] = z * Wc2[t * 2 + 0];
    r1[t] = z * Wc2[t * 2 + 1];
    __syncthreads();
    for (int s = 128; s > 0; s >>= 1) {
        if (t < s) { r0[t] += r0[t + s]; r1[t] += r1[t + s]; }
        __syncthreads();
    }
    if (t == 0) {
        out[g * 2 + 0] = r0[0] + bc2[0];
        out[g * 2 + 1] = r1[0] + bc2[1];
    }
}

// ---------------- launch ----------------

static inline size_t al256(size_t x) { return (x + 255) & ~size_t(255); }

extern "C" void kernel_launch(void* const* d_in, const int* in_sizes, int n_in,
                              void* d_out, int out_size, void* d_ws, size_t ws_size,
                              hipStream_t stream) {
    const float* x    = (const float*)d_in[0];
    const int*   ei   = (const int*)  d_in[1];
    const int*   batch= (const int*)  d_in[3];
    const float* W0a = (const float*)d_in[4];  const float* b0a = (const float*)d_in[5];
    const float* W0b = (const float*)d_in[6];  const float* b0b = (const float*)d_in[7];
    const float* W1a = (const float*)d_in[8];  const float* b1a = (const float*)d_in[9];
    const float* W1b = (const float*)d_in[10]; const float* b1b = (const float*)d_in[11];
    const float* W2a = (const float*)d_in[12]; const float* b2a = (const float*)d_in[13];
    const float* W2b = (const float*)d_in[14]; const float* b2b = (const float*)d_in[15];
    const float* Wjk = (const float*)d_in[16]; const float* bjk = (const float*)d_in[17];
    const float* Wc1 = (const float*)d_in[18]; const float* bc1 = (const float*)d_in[19];
    const float* gamma=(const float*)d_in[20]; const float* beta= (const float*)d_in[21];
    const float* rmean=(const float*)d_in[22]; const float* rvar= (const float*)d_in[23];
    const float* Wc2 = (const float*)d_in[24]; const float* bc2 = (const float*)d_in[25];
    float* out = (float*)d_out;

    const int N = NN, E = EE, B = BB;

    char* w = (char*)d_ws;
    size_t off = 0;
    int* deg    = (int*)(w + off); off = al256(off + (size_t)N * 4);
    int* rowptr = (int*)(w + off); off = al256(off + (size_t)(N + 1) * 4);
    int* bcur   = (int*)(w + off); off = al256(off + (size_t)NBKT * 4);
    int* colarr = (int*)(w + off); off = al256(off + (size_t)E * 4);
    int* ebuf   = (int*)(w + off); off = al256(off + (size_t)E * 4);
    int* bsum   = (int*)(w + off); off = al256(off + 1024 * 4);
    float* h0   = (float*)(w + off); off = al256(off + (size_t)N * 8 * 4);
    ushort* XB0 = (ushort*)(w + off); off = al256(off + (size_t)N * 128 * 2);
    ushort* XB1 = (ushort*)(w + off); off = al256(off + (size_t)N * 128 * 2);
    ushort* XB2 = (ushort*)(w + off); off = al256(off + (size_t)N * 128 * 2);
    float* pooled = (float*)(w + off); off = al256(off + (size_t)B * 128 * 4);
    ushort* wfH = (ushort*)(w + off); off = al256(off + (size_t)8 * 16384 * 2);
    ushort* wfL = (ushort*)(w + off); off = al256(off + (size_t)8 * 16384 * 2);

    hipMemsetAsync(deg, 0, (size_t)N * 4, stream);
    hipMemsetAsync(pooled, 0, (size_t)B * 128 * 4, stream);

    // pre-split weights (order: W0b, W1a, W1b, W2a, W2b, Wjk0, Wjk1, Wjk2)
    wsplit_all<<<512, 256, 0, stream>>>(W0b, W1a, W1b, W2a, W2b,
                                        Wjk, Wjk + 128 * 128, Wjk + 256 * 128,
                                        wfH, wfL);

    int nb = (N + 1023) / 1024;   // 98

    count_deg<<<(E + 255) / 256, 256, 0, stream>>>(ei, deg, E);
    scan_partial<<<nb, 256, 0, stream>>>(deg, bsum, N);
    scan_bsum<<<1, 256, 0, stream>>>(bsum, nb);
    scan_apply<<<nb, 256, 0, stream>>>(deg, bsum, rowptr, N, E);
    init_bcur<<<(NBKT + 255) / 256, 256, 0, stream>>>(rowptr, bcur);
    bin_edges2<<<(E + BIN_CHUNK - 1) / BIN_CHUNK, 256, 0, stream>>>(ei, bcur, ebuf, E);
    distribute<<<NBKT, 256, 0, stream>>>(ebuf, rowptr, colarr, N);

    int gLin = (N + 63) / 64;   // 1563

    // Layer 0: agg7 -> lin7 (bf16 t0 -> XB0) -> mlp0, x1 -> XB1 (bf16)
    agg7<<<(N + 31) / 32, 256, 0, stream>>>(x, rowptr, colarr, h0, N);
    lin7<<<(N + 7) / 8, 256, 0, stream>>>(h0, W0a, b0a, XB0, N);
    mlp_fused<false, false, false, true><<<gLin, 256, 0, stream>>>(
        XB0, rowptr, colarr,
        nullptr, nullptr, nullptr,
        wfH + 0 * 16384, wfL + 0 * 16384, b0b,
        wfH + 5 * 16384, wfL + 5 * 16384, nullptr,
        batch, XB1, pooled, N);

    // Layer 1: bf16 gather XB1 -> MLP -> x2 -> XB2 (bf16)
    mlp_fused<true, true, false, true><<<gLin, 256, 0, stream>>>(
        XB1, rowptr, colarr,
        wfH + 1 * 16384, wfL + 1 * 16384, b1a,
        wfH + 2 * 16384, wfL + 2 * 16384, b1b,
        wfH + 6 * 16384, wfL + 6 * 16384, nullptr,
        batch, XB2, pooled, N);

    // Layer 2: bf16 gather XB2 -> MLP -> jk2 (x3 never materialized)
    mlp_fused<true, true, true, false><<<gLin, 256, 0, stream>>>(
        XB2, rowptr, colarr,
        wfH + 3 * 16384, wfL + 3 * 16384, b2a,
        wfH + 4 * 16384, wfL + 4 * 16384, b2b,
        wfH + 7 * 16384, wfL + 7 * 16384, bjk,
        batch, nullptr, pooled, N);

    classifier<<<B, 256, 0, stream>>>(pooled, Wc1, bc1, gamma, beta,
                                      rmean, rvar, Wc2, bc2, out);
}

// Round 15
// 605.599 us; speedup vs baseline: 1.2582x; 1.1111x over previous
//
#include <hip/hip_runtime.h>

#define NN 100000
#define EE 1600000
#define BB 256
#define IN_F 7
#define HH 128
#define NBKT 391        // ceil(NN/256) buckets for binned CSR fill
#define BIN_CHUNK 4096  // edges per bin_edges2 block

typedef unsigned int uint;
typedef unsigned short ushort;
typedef __attribute__((ext_vector_type(8))) short short8;
typedef __attribute__((ext_vector_type(4))) float f32x4;

// ---------------- bf16 helpers ----------------

__device__ __forceinline__ float bflo(uint u) { return __uint_as_float(u << 16); }
__device__ __forceinline__ float bfhi(uint u) { return __uint_as_float(u & 0xFFFF0000u); }
__device__ __forceinline__ ushort f2bf(float x) {   // RNE; inputs finite
    uint u = __float_as_uint(x);
    u = (u + 0x7FFFu + ((u >> 16) & 1u)) >> 16;
    return (ushort)u;
}

// ---------------- CSR build ----------------

__global__ void count_deg(const int* __restrict__ ei, int* __restrict__ deg, int e) {
    int i = blockIdx.x * 256 + threadIdx.x;
    if (i < e) atomicAdd(&deg[ei[e + i]], 1);   // dst = ei[E + i]
}

__global__ void scan_partial(const int* __restrict__ deg, int* __restrict__ bsum, int n) {
    __shared__ int sd[256];
    int b = blockIdx.x, t = threadIdx.x;
    int base = b * 1024 + t * 4;
    int s = 0;
    #pragma unroll
    for (int k = 0; k < 4; ++k) { int i = base + k; if (i < n) s += deg[i]; }
    sd[t] = s; __syncthreads();
    for (int off = 128; off > 0; off >>= 1) {
        if (t < off) sd[t] += sd[t + off];
        __syncthreads();
    }
    if (t == 0) bsum[b] = sd[0];
}

__global__ void scan_bsum(int* __restrict__ bsum, int nb) {
    __shared__ int sd[256];
    int t = threadIdx.x;
    int v = (t < nb) ? bsum[t] : 0;
    sd[t] = v; __syncthreads();
    for (int off = 1; off < 256; off <<= 1) {
        int add = (t >= off) ? sd[t - off] : 0;
        __syncthreads();
        sd[t] += add;
        __syncthreads();
    }
    if (t < nb) bsum[t] = sd[t] - v;   // exclusive
}

// also writes bcur[b] = rowptr[b*256] (init_bcur folded in)
__global__ void scan_apply(const int* __restrict__ deg, const int* __restrict__ bsum,
                           int* __restrict__ rowptr, int* __restrict__ bcur, int n, int e) {
    __shared__ int sd[256];
    int b = blockIdx.x, t = threadIdx.x;
    int base = b * 1024 + t * 4;
    int v[4]; int s = 0;
    #pragma unroll
    for (int k = 0; k < 4; ++k) { int i = base + k; v[k] = (i < n) ? deg[i] : 0; s += v[k]; }
    sd[t] = s; __syncthreads();
    int mine = s;
    for (int off = 1; off < 256; off <<= 1) {
        int add = (t >= off) ? sd[t - off] : 0;
        __syncthreads();
        sd[t] += add;
        __syncthreads();
    }
    int run = sd[t] - mine + bsum[b];
    #pragma unroll
    for (int k = 0; k < 4; ++k) {
        int i = base + k;
        if (i < n) {
            rowptr[i] = run;
            if ((i & 255) == 0) bcur[i >> 8] = run;
        }
        run += v[k];
    }
    if (b == 0 && t == 0) rowptr[n] = e;
}

// Pass A (two-level): per-block LDS histogram of the 391 buckets, one global
// atomicAdd per (block,bucket) to reserve a range, then LDS-cursor scatter.
// Packed entry: src (17b) | (dst&255) << 17.
__global__ __launch_bounds__(256) void bin_edges2(const int* __restrict__ ei,
        int* __restrict__ bcur, int* __restrict__ ebuf, int e) {
    __shared__ int hist[NBKT];
    __shared__ int base[NBKT];
    int t = threadIdx.x;
    int start = blockIdx.x * BIN_CHUNK;
    int end = start + BIN_CHUNK; if (end > e) end = e;
    for (int b = t; b < NBKT; b += 256) hist[b] = 0;
    __syncthreads();
    for (int i = start + t; i < end; i += 256)
        atomicAdd(&hist[ei[e + i] >> 8], 1);
    __syncthreads();
    for (int b = t; b < NBKT; b += 256) {
        int c = hist[b];
        base[b] = (c > 0) ? atomicAdd(&bcur[b], c) : 0;
        hist[b] = 0;
    }
    __syncthreads();
    for (int i = start + t; i < end; i += 256) {
        int d = ei[e + i], s = ei[i];
        int b = d >> 8;
        int pos = base[b] + atomicAdd(&hist[b], 1);
        ebuf[pos] = s | ((d & 255) << 17);
    }
}

// Pass B: one block per bucket; LDS cursors; colarr writes confined to the
// bucket's contiguous CSR region.
__global__ __launch_bounds__(256) void distribute(const int* __restrict__ ebuf,
        const int* __restrict__ rowptr, int* __restrict__ colarr, int n) {
    __shared__ int cur[256];
    int b = blockIdx.x, t = threadIdx.x;
    int n0 = b * 256;
    int n1 = n0 + 256; if (n1 > n) n1 = n;
    if (n0 + t < n1) cur[t] = rowptr[n0 + t];
    __syncthreads();
    int ebeg = rowptr[n0], eend = rowptr[n1];
    for (int i = ebeg + t; i < eend; i += 256) {
        int v = ebuf[i];
        int pos = atomicAdd(&cur[(v >> 17) & 255], 1);
        colarr[pos] = v & 0x1FFFF;
    }
}

// ---------------- weight pre-split (all 8 matrices, one launch) ----------------
// MFMA B-fragment layout: lane holds B[k=(lane>>4)*8+j][n=lane&15], j=0..7.
// Storage: [(kc*8+nt)*64 + lane]*8 + j. hi=bf16(W), lo=bf16(W-hi).

__global__ void wsplit_all(
        const float* __restrict__ w0, const float* __restrict__ w1,
        const float* __restrict__ w2, const float* __restrict__ w3,
        const float* __restrict__ w4, const float* __restrict__ w5,
        const float* __restrict__ w6, const float* __restrict__ w7,
        ushort* __restrict__ hiB, ushort* __restrict__ loB) {
    const float* ws[8] = {w0, w1, w2, w3, w4, w5, w6, w7};
    int gidx = blockIdx.x * 256 + threadIdx.x;   // 0..131071
    int mi = gidx >> 14;
    int idx = gidx & 16383;
    int j = idx & 7, l = (idx >> 3) & 63, blk = idx >> 9;
    int kc = blk >> 3, nt = blk & 7;
    int k = kc * 32 + (l >> 4) * 8 + j;
    int n = nt * 16 + (l & 15);
    float f = ws[mi][k * 128 + n];
    ushort h = f2bf(f);
    float hf = __uint_as_float((uint)h << 16);
    hiB[gidx] = h;
    loB[gidx] = f2bf(f - hf);
}

// ---------------- layer-0 aggregation (d=7) ----------------

__global__ __launch_bounds__(256) void agg7(const float* __restrict__ xin,
        const int* __restrict__ rowptr, const int* __restrict__ colarr,
        float* __restrict__ h0, int n) {
    int node = blockIdx.x * 32 + (threadIdx.x >> 3);
    int f = threadIdx.x & 7;
    if (node >= n) return;
    int fidx = (f < 7) ? f : 0;
    float acc = xin[node * 7 + fidx];
    int beg = rowptr[node], end = rowptr[node + 1];
    int j = beg;
    for (; j + 4 <= end; j += 4) {
        int s0 = colarr[j], s1 = colarr[j+1], s2 = colarr[j+2], s3 = colarr[j+3];
        float v0 = xin[s0*7 + fidx], v1 = xin[s1*7 + fidx];
        float v2 = xin[s2*7 + fidx], v3 = xin[s3*7 + fidx];
        acc += (v0 + v1) + (v2 + v3);
    }
    for (; j < end; ++j) acc += xin[colarr[j]*7 + fidx];
    h0[node * 8 + f] = (f < 7) ? acc : 0.f;
}

// ---------------- small first linear (bf16 output) ----------------

__global__ __launch_bounds__(256) void lin7(const float* __restrict__ h0,
        const float* __restrict__ W, const float* __restrict__ bias,
        ushort* __restrict__ out, int n) {
    __shared__ float wl[7][128];
    __shared__ float hl[8][8];
    int t = threadIdx.x;
    for (int l = t; l < 7 * 128; l += 256) wl[l >> 7][l & 127] = W[l];
    int row0 = blockIdx.x * 8;
    if (t < 64) {
        int r = t >> 3, k = t & 7;
        int gr = row0 + r;
        hl[r][k] = (gr < n) ? h0[gr * 8 + k] : 0.f;
    }
    __syncthreads();
    int c = t & 127, g = t >> 7;
    float bv = bias[c];
    #pragma unroll
    for (int i = 0; i < 4; ++i) {
        int r = g * 4 + i, gr = row0 + r;
        if (gr < n) {
            float acc = bv;
            #pragma unroll
            for (int k = 0; k < 7; ++k) acc += hl[r][k] * wl[k][c];
            out[gr * 128 + c] = f2bf(fmaxf(acc, 0.f));
        }
    }
}

// ------- fused [bf16 aggregate] + MFMA MLP + JK + pool (256 thr = 4 waves) -------

__device__ __forceinline__ int swz(int r) { return ((r >> 2) & 7) * 4; }

__device__ __forceinline__ void gemm_mfma(
        const ushort* __restrict__ WH, const ushort* __restrict__ WL,
        const float (&a_lds)[64][128], int mt, int lm, int lq, int l,
        f32x4 (&acc)[8])
{
    #pragma unroll
    for (int nt = 0; nt < 8; ++nt) acc[nt] = (f32x4){0.f, 0.f, 0.f, 0.f};
    const short8* BH = (const short8*)WH;
    const short8* BL = (const short8*)WL;
    int m = mt + lm;
    int s = swz(m);
    #pragma unroll
    for (int kc = 0; kc < 4; ++kc) {
        int cb = kc * 32 + lq * 8;
        float4 a0 = *(const float4*)&a_lds[m][cb ^ s];
        float4 a1 = *(const float4*)&a_lds[m][(cb + 4) ^ s];
        float av[8] = {a0.x, a0.y, a0.z, a0.w, a1.x, a1.y, a1.z, a1.w};
        short8 ah, al8;
        #pragma unroll
        for (int j = 0; j < 8; ++j) {
            ushort h = f2bf(av[j]);
            ah[j] = (short)h;
            float hf = __uint_as_float((uint)h << 16);
            al8[j] = (short)f2bf(av[j] - hf);
        }
        #pragma unroll
        for (int nt = 0; nt < 8; ++nt) {
            short8 bh = BH[(kc * 8 + nt) * 64 + l];
            short8 bl = BL[(kc * 8 + nt) * 64 + l];
            acc[nt] = __builtin_amdgcn_mfma_f32_16x16x32_bf16(ah,  bh, acc[nt], 0, 0, 0);
            acc[nt] = __builtin_amdgcn_mfma_f32_16x16x32_bf16(al8, bh, acc[nt], 0, 0, 0);
            acc[nt] = __builtin_amdgcn_mfma_f32_16x16x32_bf16(ah,  bl, acc[nt], 0, 0, 0);
        }
    }
}

__device__ __forceinline__ void epi_store(f32x4 (&acc)[8], const float* __restrict__ bias,
        float (&a_lds)[64][128], int row0, int n, int mt, int lm, int lq,
        ushort* __restrict__ xout)
{
    #pragma unroll
    for (int nt = 0; nt < 8; ++nt) {
        int col = nt * 16 + lm;
        float bv = bias[col];
        #pragma unroll
        for (int r = 0; r < 4; ++r) {
            int row = mt + lq * 4 + r;
            int gr = row0 + row;
            float v = fmaxf(acc[nt][r] + bv, 0.f);
            if (gr >= n) v = 0.f;
            a_lds[row][col ^ swz(row)] = v;
            if (xout != nullptr && gr < n)
                xout[(size_t)gr * 128 + col] = f2bf(v);
        }
    }
}

template<bool GATHER, bool DO_A, bool LASTB, bool WRITE_X>
__global__ __launch_bounds__(256) void mlp_fused(
        const ushort* __restrict__ in_bf,
        const int* __restrict__ rowptr, const int* __restrict__ colarr,
        const ushort* __restrict__ WaH, const ushort* __restrict__ WaL,
        const float* __restrict__ ba,
        const ushort* __restrict__ WbH, const ushort* __restrict__ WbL,
        const float* __restrict__ bb,
        const ushort* __restrict__ WjH, const ushort* __restrict__ WjL,
        const float* __restrict__ bjk,
        const int* __restrict__ batch,
        ushort* __restrict__ xout_bf, float* __restrict__ pooled, int n)
{
    __shared__ float a_lds[64][128];   // 32 KB
    int t = threadIdx.x;
    int row0 = blockIdx.x * 64;

    if (GATHER) {
        // R12 gather (empirical optimum: x2 unroll, VGPR 80): LDS-staged indices,
        // 8 outstanding 16B loads/thread. x4 unroll (R14) and balanced-walk (R13)
        // both regressed via occupancy / MLP loss.
        int* idx_lds = (int*)&a_lds[0][0];      // capacity 8192 ints
        int rlast = row0 + 64; if (rlast > n) rlast = n;
        int eb = rowptr[row0];
        int cnt = rowptr[rlast] - eb;
        int staged = cnt < 8192 ? cnt : 8192;
        for (int i = t; i < staged; i += 256) idx_lds[i] = colarr[eb + i];
        __syncthreads();

        int r = t >> 2, q = t & 3;
        int gr = row0 + r;
        float f[4][8];
        #pragma unroll
        for (int i = 0; i < 4; ++i)
            #pragma unroll
            for (int j = 0; j < 8; ++j) f[i][j] = 0.f;
        if (gr < n) {
            const uint4* sp = (const uint4*)(in_bf + (size_t)gr * 128);
            #pragma unroll
            for (int i = 0; i < 4; ++i) {
                uint4 v = sp[i * 4 + q];
                f[i][0] = bflo(v.x); f[i][1] = bfhi(v.x);
                f[i][2] = bflo(v.y); f[i][3] = bfhi(v.y);
                f[i][4] = bflo(v.z); f[i][5] = bfhi(v.z);
                f[i][6] = bflo(v.w); f[i][7] = bfhi(v.w);
            }
            int beg = rowptr[gr] - eb, end = rowptr[gr + 1] - eb;
            int j = beg;
            for (; j + 2 <= end; j += 2) {
                int s0 = (j     < staged) ? idx_lds[j]     : colarr[eb + j];
                int s1 = (j + 1 < staged) ? idx_lds[j + 1] : colarr[eb + j + 1];
                const uint4* n0 = (const uint4*)(in_bf + (size_t)s0 * 128);
                const uint4* n1 = (const uint4*)(in_bf + (size_t)s1 * 128);
                uint4 v0[4], v1[4];
                #pragma unroll
                for (int i = 0; i < 4; ++i) { v0[i] = n0[i * 4 + q]; v1[i] = n1[i * 4 + q]; }
                #pragma unroll
                for (int i = 0; i < 4; ++i) {
                    f[i][0] += bflo(v0[i].x) + bflo(v1[i].x);
                    f[i][1] += bfhi(v0[i].x) + bfhi(v1[i].x);
                    f[i][2] += bflo(v0[i].y) + bflo(v1[i].y);
                    f[i][3] += bfhi(v0[i].y) + bfhi(v1[i].y);
                    f[i][4] += bflo(v0[i].z) + bflo(v1[i].z);
                    f[i][5] += bfhi(v0[i].z) + bfhi(v1[i].z);
                    f[i][6] += bflo(v0[i].w) + bflo(v1[i].w);
                    f[i][7] += bfhi(v0[i].w) + bfhi(v1[i].w);
                }
            }
            for (; j < end; ++j) {
                int s0 = (j < staged) ? idx_lds[j] : colarr[eb + j];
                const uint4* np = (const uint4*)(in_bf + (size_t)s0 * 128);
                #pragma unroll
                for (int i = 0; i < 4; ++i) {
                    uint4 v = np[i * 4 + q];
                    f[i][0] += bflo(v.x); f[i][1] += bfhi(v.x);
                    f[i][2] += bflo(v.y); f[i][3] += bfhi(v.y);
                    f[i][4] += bflo(v.z); f[i][5] += bfhi(v.z);
                    f[i][6] += bflo(v.w); f[i][7] += bfhi(v.w);
                }
            }
        }
        __syncthreads();   // all idx_lds reads done before a_lds is overwritten
        int s = swz(r);
        #pragma unroll
        for (int i = 0; i < 4; ++i) {
            int c = (i * 4 + q) * 8;
            *(float4*)&a_lds[r][c ^ s]       = make_float4(f[i][0], f[i][1], f[i][2], f[i][3]);
            *(float4*)&a_lds[r][(c + 4) ^ s] = make_float4(f[i][4], f[i][5], f[i][6], f[i][7]);
        }
    } else {
        // bf16 staging of t0 (no gather): 1024 uint4 = 64 rows x 16 chunks
        #pragma unroll
        for (int it = 0; it < 4; ++it) {
            int l = t + 256 * it;
            int r = l >> 4, c8 = (l & 15) * 8;
            int gr = row0 + r;
            uint4 v = make_uint4(0u, 0u, 0u, 0u);
            if (gr < n) v = *(const uint4*)&in_bf[(size_t)gr * 128 + c8];
            int s = swz(r);
            *(float4*)&a_lds[r][c8 ^ s] =
                make_float4(bflo(v.x), bfhi(v.x), bflo(v.y), bfhi(v.y));
            *(float4*)&a_lds[r][(c8 + 4) ^ s] =
                make_float4(bflo(v.z), bfhi(v.z), bflo(v.w), bfhi(v.w));
        }
    }
    __syncthreads();

    int w = t >> 6, l = t & 63;
    int mt = w * 16, lm = l & 15, lq = l >> 4;
    f32x4 acc[8];

    if (DO_A) {
        gemm_mfma(WaH, WaL, a_lds, mt, lm, lq, l, acc);
        __syncthreads();
        epi_store(acc, ba, a_lds, row0, n, mt, lm, lq, nullptr);
        __syncthreads();
    }

    gemm_mfma(WbH, WbL, a_lds, mt, lm, lq, l, acc);
    __syncthreads();
    epi_store(acc, bb, a_lds, row0, n, mt, lm, lq, WRITE_X ? xout_bf : nullptr);
    __syncthreads();

    gemm_mfma(WjH, WjL, a_lds, mt, lm, lq, l, acc);
    __syncthreads();

    // JK epilogue: +bjk (last layer), mask invalid rows, stage y into a_lds
    #pragma unroll
    for (int nt = 0; nt < 8; ++nt) {
        int col = nt * 16 + lm;
        float bv = LASTB ? bjk[col] : 0.f;
        #pragma unroll
        for (int r = 0; r < 4; ++r) {
            int row = mt + lq * 4 + r;
            int gr = row0 + row;
            float v = acc[nt][r] + bv;
            if (gr >= n) v = 0.f;
            a_lds[row][col ^ swz(row)] = v;
        }
    }
    __syncthreads();

    // pooling
    int row_last = row0 + 63; if (row_last > n - 1) row_last = n - 1;
    int g_first = batch[row0];
    int g_last  = batch[row_last];
    int c = t & 127, half = t >> 7;
    if (g_first == g_last) {
        float sacc = 0.f;
        for (int r = half * 32; r < half * 32 + 32; ++r)
            sacc += a_lds[r][c ^ swz(r)];
        __syncthreads();
        a_lds[half][c] = sacc;
        __syncthreads();
        if (t < 128)
            atomicAdd(&pooled[g_first * 128 + t], a_lds[0][t] + a_lds[1][t]);
    } else {
        float sacc = 0.f; int gprev = -1;
        for (int r = half * 32; r < half * 32 + 32; ++r) {
            int gr = row0 + r;
            if (gr >= n) break;
            int g = batch[gr];
            if (g != gprev) {
                if (gprev >= 0) atomicAdd(&pooled[gprev * 128 + c], sacc);
                sacc = 0.f; gprev = g;
            }
            sacc += a_lds[r][c ^ swz(r)];
        }
        if (gprev >= 0) atomicAdd(&pooled[gprev * 128 + c], sacc);
    }
}

// ---------------- classifier ----------------

__global__ __launch_bounds__(256) void classifier(const float* __restrict__ pooled,
        const float* __restrict__ Wc1, const float* __restrict__ bc1,
        const float* __restrict__ gamma, const float* __restrict__ beta,
        const float* __restrict__ rmean, const float* __restrict__ rvar,
        const float* __restrict__ Wc2, const float* __restrict__ bc2,
        float* __restrict__ out) {
    int g = blockIdx.x, t = threadIdx.x;
    __shared__ float p[128];
    __shared__ float r0[256], r1[256];
    if (t < 128) p[t] = pooled[g * 128 + t];
    __syncthreads();
    float acc = bc1[t];
    #pragma unroll 8
    for (int k = 0; k < 128; ++k) acc += p[k] * Wc1[k * 256 + t];
    float z = (acc - rmean[t]) * rsqrtf(rvar[t] + 1e-5f) * gamma[t] + beta[t];
    z = fmaxf(z, 0.f);
    r0[t] = z * Wc2[t * 2 + 0];
    r1[t] = z * Wc2[t * 2 + 1];
    __syncthreads();
    for (int s = 128; s > 0; s >>= 1) {
        if (t < s) { r0[t] += r0[t + s]; r1[t] += r1[t + s]; }
        __syncthreads();
    }
    if (t == 0) {
        out[g * 2 + 0] = r0[0] + bc2[0];
        out[g * 2 + 1] = r1[0] + bc2[1];
    }
}

// ---------------- launch ----------------

static inline size_t al256(size_t x) { return (x + 255) & ~size_t(255); }

extern "C" void kernel_launch(void* const* d_in, const int* in_sizes, int n_in,
                              void* d_out, int out_size, void* d_ws, size_t ws_size,
                              hipStream_t stream) {
    const float* x    = (const float*)d_in[0];
    const int*   ei   = (const int*)  d_in[1];
    const int*   batch= (const int*)  d_in[3];
    const float* W0a = (const float*)d_in[4];  const float* b0a = (const float*)d_in[5];
    const float* W0b = (const float*)d_in[6];  const float* b0b = (const float*)d_in[7];
    const float* W1a = (const float*)d_in[8];  const float* b1a = (const float*)d_in[9];
    const float* W1b = (const float*)d_in[10]; const float* b1b = (const float*)d_in[11];
    const float* W2a = (const float*)d_in[12]; const float* b2a = (const float*)d_in[13];
    const float* W2b = (const float*)d_in[14]; const float* b2b = (const float*)d_in[15];
    const float* Wjk = (const float*)d_in[16]; const float* bjk = (const float*)d_in[17];
    const float* Wc1 = (const float*)d_in[18]; const float* bc1 = (const float*)d_in[19];
    const float* gamma=(const float*)d_in[20]; const float* beta= (const float*)d_in[21];
    const float* rmean=(const float*)d_in[22]; const float* rvar= (const float*)d_in[23];
    const float* Wc2 = (const float*)d_in[24]; const float* bc2 = (const float*)d_in[25];
    float* out = (float*)d_out;

    const int N = NN, E = EE, B = BB;

    char* w = (char*)d_ws;
    size_t off = 0;
    int* deg    = (int*)(w + off); off = al256(off + (size_t)N * 4);
    int* rowptr = (int*)(w + off); off = al256(off + (size_t)(N + 1) * 4);
    int* bcur   = (int*)(w + off); off = al256(off + (size_t)NBKT * 4);
    int* colarr = (int*)(w + off); off = al256(off + (size_t)E * 4);
    int* ebuf   = (int*)(w + off); off = al256(off + (size_t)E * 4);
    int* bsum   = (int*)(w + off); off = al256(off + 1024 * 4);
    float* h0   = (float*)(w + off); off = al256(off + (size_t)N * 8 * 4);
    ushort* XB0 = (ushort*)(w + off); off = al256(off + (size_t)N * 128 * 2);
    ushort* XB1 = (ushort*)(w + off); off = al256(off + (size_t)N * 128 * 2);
    ushort* XB2 = (ushort*)(w + off); off = al256(off + (size_t)N * 128 * 2);
    float* pooled = (float*)(w + off); off = al256(off + (size_t)B * 128 * 4);
    ushort* wfH = (ushort*)(w + off); off = al256(off + (size_t)8 * 16384 * 2);
    ushort* wfL = (ushort*)(w + off); off = al256(off + (size_t)8 * 16384 * 2);

    hipMemsetAsync(deg, 0, (size_t)N * 4, stream);
    hipMemsetAsync(pooled, 0, (size_t)B * 128 * 4, stream);

    // pre-split weights (order: W0b, W1a, W1b, W2a, W2b, Wjk0, Wjk1, Wjk2)
    wsplit_all<<<512, 256, 0, stream>>>(W0b, W1a, W1b, W2a, W2b,
                                        Wjk, Wjk + 128 * 128, Wjk + 256 * 128,
                                        wfH, wfL);

    int nb = (N + 1023) / 1024;   // 98

    count_deg<<<(E + 255) / 256, 256, 0, stream>>>(ei, deg, E);
    scan_partial<<<nb, 256, 0, stream>>>(deg, bsum, N);
    scan_bsum<<<1, 256, 0, stream>>>(bsum, nb);
    scan_apply<<<nb, 256, 0, stream>>>(deg, bsum, rowptr, bcur, N, E);
    bin_edges2<<<(E + BIN_CHUNK - 1) / BIN_CHUNK, 256, 0, stream>>>(ei, bcur, ebuf, E);
    distribute<<<NBKT, 256, 0, stream>>>(ebuf, rowptr, colarr, N);

    int gLin = (N + 63) / 64;   // 1563

    // Layer 0: agg7 -> lin7 (bf16 t0 -> XB0) -> mlp0, x1 -> XB1 (bf16)
    agg7<<<(N + 31) / 32, 256, 0, stream>>>(x, rowptr, colarr, h0, N);
    lin7<<<(N + 7) / 8, 256, 0, stream>>>(h0, W0a, b0a, XB0, N);
    mlp_fused<false, false, false, true><<<gLin, 256, 0, stream>>>(
        XB0, rowptr, colarr,
        nullptr, nullptr, nullptr,
        wfH + 0 * 16384, wfL + 0 * 16384, b0b,
        wfH + 5 * 16384, wfL + 5 * 16384, nullptr,
        batch, XB1, pooled, N);

    // Layer 1: bf16 gather XB1 -> MLP -> x2 -> XB2 (bf16)
    mlp_fused<true, true, false, true><<<gLin, 256, 0, stream>>>(
        XB1, rowptr, colarr,
        wfH + 1 * 16384, wfL + 1 * 16384, b1a,
        wfH + 2 * 16384, wfL + 2 * 16384, b1b,
        wfH + 6 * 16384, wfL + 6 * 16384, nullptr,
        batch, XB2, pooled, N);

    // Layer 2: bf16 gather XB2 -> MLP -> jk2 (x3 never materialized)
    mlp_fused<true, true, true, false><<<gLin, 256, 0, stream>>>(
        XB2, rowptr, colarr,
        wfH + 3 * 16384, wfL + 3 * 16384, b2a,
        wfH + 4 * 16384, wfL + 4 * 16384, b2b,
        wfH + 7 * 16384, wfL + 7 * 16384, bjk,
        batch, nullptr, pooled, N);

    classifier<<<B, 256, 0, stream>>>(pooled, Wc1, bc1, gamma, beta,
                                      rmean, rvar, Wc2, bc2, out);
}